// Round 10
// baseline (21797.229 us; speedup 1.0000x reference)
//
#include <hip/hip_runtime.h>
#include <hip/hip_fp16.h>
#include <cmath>

typedef _Float16 f16;
typedef _Float16 half8 __attribute__((ext_vector_type(8)));
typedef float f32x4 __attribute__((ext_vector_type(4)));

#define P_WG   25          // workgroups per direction (24 hidden units each)
#define GRID_MAIN (2*P_WG) // 50
#define G      12          // XZ lookahead distance
#define RING   13          // XZ ring slots (G+1)

#define X16_ELEMS  (64u*512u*320u)          // 10,485,760 f16 per plane
#define WPK_PAIR   (2u*25u*6u*10u*512u)     // 1,536,000 iter (each writes hi+lo)
#define WPK_TOFF   30720u                   // term stride = 6*10*512
#define UPK_ELEMS  (2u*25u*6u*19u*512u)     // 2,918,400 f16 (hi only)
#define HBUF_WORDS (2u*2u*64u*640u/2u)      // 81,920 u32
#define FLAG_WORDS 1024u                    // 2 dirs x 32 slots x 16-word stride

// ---------------- prep: rebuild all workspace state every launch ----------------
__global__ void lstm_prep(const float* __restrict__ x,
                          const float* __restrict__ Wf, const float* __restrict__ Uf,
                          const float* __restrict__ Wb, const float* __restrict__ Ub,
                          const int* __restrict__ len,
                          f16* __restrict__ x16h, f16* __restrict__ x16l,
                          f16* __restrict__ Wpk, f16* __restrict__ Upk,
                          unsigned* __restrict__ hbw, unsigned* __restrict__ flags,
                          int* __restrict__ maxT, float* __restrict__ outp)
{
    const unsigned total = X16_ELEMS + WPK_PAIR + UPK_ELEMS + HBUF_WORDS + FLAG_WORDS + 2u;
    for (unsigned e = blockIdx.x * blockDim.x + threadIdx.x; e < total;
         e += gridDim.x * blockDim.x) {
        if (e < X16_ELEMS) {
            unsigned k = e % 320u, r = e / 320u;   // r = b*512 + t
            float v = (k < 300u) ? x[r * 300u + k] : 0.0f;
            f16 hi = (f16)v;
            x16h[e] = hi;
            x16l[e] = (f16)((v - (float)hi) * 2048.0f);
        } else if (e < X16_ELEMS + WPK_PAIR) {
            // W fragments: [dir][p25][term2][ntx6][kt10][lane][8]
            unsigned i = e - X16_ELEMS;
            unsigned j    = i & 7u,  r1 = i >> 3;
            unsigned lane = r1 & 63u, r2 = r1 >> 6;
            unsigned kt   = r2 % 10u, r3 = r2 / 10u;
            unsigned ntx  = r3 % 6u,  r4 = r3 / 6u;
            unsigned p    = r4 % 25u, dw = r4 / 25u;
            unsigned k    = kt * 32u + (lane >> 4) * 8u + j;
            unsigned l15  = lane & 15u;
            unsigned gate = (ntx & 1u) * 2u + (l15 >> 3);
            unsigned c    = gate * 600u + p * 24u + (ntx >> 1) * 8u + (l15 & 7u);
            float v = (k < 300u) ? (dw ? Wb : Wf)[k * 2400u + c] : 0.0f;
            f16 hi = (f16)v;
            unsigned base = ((((dw * 25u + p) * 2u + 0u) * 6u + ntx) * 10u + kt) * 512u + (i & 511u);
            Wpk[base]            = hi;
            Wpk[base + WPK_TOFF] = (f16)((v - (float)hi) * 2048.0f); // lo pre-scaled 2^11
        } else if (e < X16_ELEMS + WPK_PAIR + UPK_ELEMS) {
            // U fragments (hi only): [dir][p25][ntx6][kt19][lane][8]
            unsigned i = e - X16_ELEMS - WPK_PAIR;
            unsigned j    = i & 7u,  r1 = i >> 3;
            unsigned lane = r1 & 63u, r2 = r1 >> 6;
            unsigned kt   = r2 % 19u, r3 = r2 / 19u;
            unsigned ntx  = r3 % 6u,  r4 = r3 / 6u;
            unsigned p    = r4 % 25u, dw = r4 / 25u;
            unsigned k    = kt * 32u + (lane >> 4) * 8u + j;   // 0..607
            unsigned l15  = lane & 15u;
            unsigned gate = (ntx & 1u) * 2u + (l15 >> 3);
            unsigned c    = gate * 600u + p * 24u + (ntx >> 1) * 8u + (l15 & 7u);
            float v = (k < 600u) ? (dw ? Ub : Uf)[k * 2400u + c] : 0.0f;
            Upk[(((dw * 25u + p) * 6u + ntx) * 19u + kt) * 512u + (i & 511u)] = (f16)v;
        } else if (e < X16_ELEMS + WPK_PAIR + UPK_ELEMS + HBUF_WORDS) {
            hbw[e - X16_ELEMS - WPK_PAIR - UPK_ELEMS] = 0u;   // zero h ping-pong buffers
        } else if (e < X16_ELEMS + WPK_PAIR + UPK_ELEMS + HBUF_WORDS + FLAG_WORDS) {
            flags[e - (X16_ELEMS + WPK_PAIR + UPK_ELEMS + HBUF_WORDS)] = 0u;
        } else {
            unsigned q = e - (X16_ELEMS + WPK_PAIR + UPK_ELEMS + HBUF_WORDS + FLAG_WORDS);
            if (q == 0u) {
                int m = 1;
                for (int b = 0; b < 64; ++b) { int L = len[b]; m = (L > m) ? L : m; }
                *maxT = m;
            } else {
                outp[0] = 1000.0f;   // sentinel: lstm_main always overwrites out[0]
            }
        }
    }
}

// MALL-direct 16B load as 2x8B agent-scope atomic loads (bypass L1/L2 -> always fresh)
__device__ __forceinline__ half8 ld_h8_mall(const f16* p) {
    union { unsigned long long u[2]; half8 h; } x;
    x.u[0] = __hip_atomic_load((const unsigned long long*)p,     __ATOMIC_RELAXED, __HIP_MEMORY_SCOPE_AGENT);
    x.u[1] = __hip_atomic_load((const unsigned long long*)p + 1, __ATOMIC_RELAXED, __HIP_MEMORY_SCOPE_AGENT);
    return x.h;
}

// ---------------- main persistent recurrent kernel ----------------
__global__ __launch_bounds__(256, 1)
void lstm_main(const f16* __restrict__ x16h, const f16* __restrict__ x16l,
               const f16* __restrict__ Wpk, const f16* __restrict__ Upk,
               f16* __restrict__ hbuf, float* __restrict__ xz,
               unsigned* flags, const int* __restrict__ maxT,
               const int* __restrict__ len,
               const float* __restrict__ bfv, const float* __restrict__ bbv,
               float* __restrict__ out)
{
    __shared__ f16 Ulds[6 * 19 * 512];     // 116,736 B: resident U-hi fragments
    __shared__ f32x4 obox[4][4][2][64];    // 32 KB merge buffer (chunked over ntx pairs)
    __shared__ f16 hstage[64][32];         // 4 KB (padded stride 64B -> 2-way free)

    const int tid  = threadIdx.x;
    const int wave = tid >> 6, lane = tid & 63;
    const int quad = lane >> 4, l15 = lane & 15;
    const int dir  = blockIdx.x & 1, p = blockIdx.x >> 1;

    // ---- load this WG's U fragments into LDS (once) ----
    {
        const half8* src = (const half8*)(Upk + (size_t)(dir * 25 + p) * 6u * 19u * 512u);
        half8* dst = (half8*)Ulds;
        for (int e2 = tid; e2 < 6 * 19 * 512 / 8; e2 += 256) dst[e2] = src[e2];
    }

    const float* bias = dir ? bbv : bfv;
    float bz[6];
#pragma unroll
    for (int ntx = 0; ntx < 6; ++ntx) {
        int gate = (ntx & 1) * 2 + (l15 >> 3);
        bz[ntx] = bias[gate * 600 + p * 24 + (ntx >> 1) * 8 + (l15 & 7)];
    }
    const int Lw = len[wave * 16 + l15];   // burst A rows
    int Lr[4];
#pragma unroll
    for (int r = 0; r < 4; ++r) Lr[r] = len[wave * 16 + quad * 4 + r]; // epilogue rows

    f16* hb0 = hbuf + dir * (2 * 64 * 640);
    unsigned* myflag = flags + dir * 512 + p * 16;   // own 64B line per WG
    float* myxz = xz + (size_t)blockIdx.x * (RING * 64 * 96);
    float cst[3][4] = {{0,0,0,0},{0,0,0,0},{0,0,0,0}};
    float sum[3][4] = {{0,0,0,0},{0,0,0,0},{0,0,0,0}};
    const int T = *maxT;
    const f16* wbase = Wpk + (size_t)(dir * 25 + p) * 2u * 6u * 10u * 512u;

    // burst: XZ(tt) = x_tt * W + b for this wave's 16 batch rows, 96 cols
    auto burst = [&](int slot, int tt) {
        int tx = tt;
        if (dir) tx = (tt < Lw) ? (Lw - 1 - tt) : tt;   // reverse_sequence
        unsigned arow = ((unsigned)(wave * 16 + l15) * 512u + (unsigned)tx) * 320u + quad * 8;
        f32x4 aH[6], aM[6];
#pragma unroll
        for (int ntx = 0; ntx < 6; ++ntx) {
            aH[ntx] = f32x4{0.f, 0.f, 0.f, 0.f};
            aM[ntx] = f32x4{0.f, 0.f, 0.f, 0.f};
        }
#pragma unroll
        for (int kt = 0; kt < 10; ++kt) {
            half8 Ah = *(const half8*)(x16h + arow + kt * 32);
            half8 Al = *(const half8*)(x16l + arow + kt * 32);
#pragma unroll
            for (int ntx = 0; ntx < 6; ++ntx) {
                const f16* bb = Wpk ? wbase + ((unsigned)(ntx * 10 + kt)) * 512u + lane * 8 : nullptr;
                half8 Bhi = *(const half8*)bb;
                half8 Blo = *(const half8*)(bb + WPK_TOFF);
                aH[ntx] = __builtin_amdgcn_mfma_f32_16x16x32_f16(Ah, Bhi, aH[ntx], 0, 0, 0);
                aM[ntx] = __builtin_amdgcn_mfma_f32_16x16x32_f16(Ah, Blo, aM[ntx], 0, 0, 0);
                aM[ntx] = __builtin_amdgcn_mfma_f32_16x16x32_f16(Al, Bhi, aM[ntx], 0, 0, 0);
            }
        }
#pragma unroll
        for (int ntx = 0; ntx < 6; ++ntx)
#pragma unroll
            for (int r = 0; r < 4; ++r)
                myxz[(unsigned)(slot * 64 + wave * 16 + quad * 4 + r) * 96u + ntx * 16 + l15] =
                    aH[ntx][r] + aM[ntx][r] * (1.0f / 2048.0f) + bz[ntx];
    };

    // initial fill: each wave fills its own rows for slots 0..G-1 (no barrier needed)
    for (int g = 0; g < G; ++g) burst(g, g);

    for (int t = 0; t < T; ++t) {
        // ---- pipelined burst for step t+G (overlaps the notify chain) ----
        if (t + G < T) burst((t + G) % RING, t + G);

        const f16* hcur = hb0 + (t & 1) * (64 * 640);
        f16*       hnxt = hb0 + ((t + 1) & 1) * (64 * 640);

        // ---- wait: wave 0, 25 lanes each polling their own 64B flag line ----
        if (t > 0 && wave == 0) {
            const unsigned tgt = (unsigned)t;
            for (;;) {
                unsigned v = 0xFFFFFFFFu;
                if (lane < 25)
                    v = __hip_atomic_load(flags + dir * 512 + lane * 16,
                                          __ATOMIC_RELAXED, __HIP_MEMORY_SCOPE_AGENT);
                if (!__any(v < tgt)) break;
                __builtin_amdgcn_s_sleep(1);
            }
            __builtin_amdgcn_fence(__ATOMIC_ACQUIRE, "workgroup"); // order only; no cache inv
        }
        __syncthreads();   // B1

        // ---- prefetch all h fragments (all MALL loads in flight together) ----
        half8 Ahh[5][4];
#pragma unroll
        for (int sp = 0; sp < 5; ++sp) {
            int kt = wave + 4 * sp;
            if (kt < 19) {
#pragma unroll
                for (int mt = 0; mt < 4; ++mt)
                    Ahh[sp][mt] = ld_h8_mall(hcur + (unsigned)(mt * 16 + l15) * 640u + kt * 32 + quad * 8);
            }
        }

        // ---- h-part MFMAs + chunked K-merge (3 chunks of 2 ntx) ----
        f32x4 z[6];
#pragma unroll
        for (int c = 0; c < 3; ++c) {
            f32x4 acc[4][2];
#pragma unroll
            for (int mt = 0; mt < 4; ++mt)
#pragma unroll
                for (int i2 = 0; i2 < 2; ++i2)
                    acc[mt][i2] = f32x4{0.f, 0.f, 0.f, 0.f};
#pragma unroll
            for (int sp = 0; sp < 5; ++sp) {
                int kt = wave + 4 * sp;
                if (kt < 19) {
#pragma unroll
                    for (int i2 = 0; i2 < 2; ++i2) {
                        int ntx = 2 * c + i2;
                        half8 B = *(const half8*)&Ulds[(unsigned)(ntx * 19 + kt) * 512u + lane * 8];
#pragma unroll
                        for (int mt = 0; mt < 4; ++mt)
                            acc[mt][i2] = __builtin_amdgcn_mfma_f32_16x16x32_f16(Ahh[sp][mt], B, acc[mt][i2], 0, 0, 0);
                    }
                }
            }
#pragma unroll
            for (int mt = 0; mt < 4; ++mt)
#pragma unroll
                for (int i2 = 0; i2 < 2; ++i2)
                    obox[wave][mt][i2][lane] = acc[mt][i2];
            __syncthreads();   // obox write -> read
#pragma unroll
            for (int i2 = 0; i2 < 2; ++i2)
                z[2 * c + i2] = obox[0][wave][i2][lane] + obox[1][wave][i2][lane]
                              + obox[2][wave][i2][lane] + obox[3][wave][i2][lane];
            __syncthreads();   // protect obox before next chunk
        }

        // ---- add XZ (loaded late to cut register pressure; WG-local, L1-warm) ----
        {
            unsigned rbase = (unsigned)((t % RING) * 64 + wave * 16 + quad * 4) * 96u;
#pragma unroll
            for (int ntx = 0; ntx < 6; ++ntx) {
                f32x4 zz;
#pragma unroll
                for (int r = 0; r < 4; ++r)
                    zz[r] = myxz[rbase + r * 96 + ntx * 16 + l15];
                z[ntx] += zz;
            }
        }

        // ---- epilogue: rows wave*16..+15, 24 hidden cols (3 oct-groups) ----
#pragma unroll
        for (int og = 0; og < 3; ++og) {
#pragma unroll
            for (int r = 0; r < 4; ++r) {
                float zi = z[og * 2][r],     zg = z[og * 2 + 1][r];
                float zf = __shfl_xor(z[og * 2][r], 8, 64);      // f gate 8 lanes over
                float zo = __shfl_xor(z[og * 2 + 1][r], 8, 64);
                if (l15 < 8) {
                    float ig = 1.0f / (1.0f + __expf(-zi));
                    float fg = 1.0f / (1.0f + __expf(-zf));
                    float gg = tanhf(zg);
                    float og_ = 1.0f / (1.0f + __expf(-zo));
                    float cc = fg * cst[og][r] + ig * gg;
                    cst[og][r] = cc;
                    float h = og_ * tanhf(cc);
                    if (t < Lr[r]) sum[og][r] += h;
                    hstage[wave * 16 + quad * 4 + r][og * 8 + l15] = (f16)h;
                }
            }
        }
        __syncthreads();   // B3: hstage ready; waves 1-3 run ahead to next burst

        // ---- wave 0 publishes h (3 KB: 64 rows x 48B) + release-stores its flag ----
        if (wave == 0) {
            const unsigned long long* hs = (const unsigned long long*)&hstage[lane][0];
            unsigned long long* dst = (unsigned long long*)(hnxt + (unsigned)lane * 640u + p * 24);
#pragma unroll
            for (int q = 0; q < 6; ++q)
                __hip_atomic_store(dst + q, hs[q], __ATOMIC_RELAXED, __HIP_MEMORY_SCOPE_AGENT);
            if (lane == 0)
                __hip_atomic_store(myflag, (unsigned)(t + 1),
                                   __ATOMIC_RELEASE, __HIP_MEMORY_SCOPE_AGENT);
        }
    }

    // ---- output: masked mean over the sequence ----
#pragma unroll
    for (int og = 0; og < 3; ++og) {
        if (l15 < 8) {
#pragma unroll
            for (int r = 0; r < 4; ++r)
                out[(wave * 16 + quad * 4 + r) * 1200 + dir * 600 + p * 24 + og * 8 + l15] =
                    sum[og][r] * (1.0f / 512.0f);
        }
    }
}

// ---------------- launcher ----------------
extern "C" void kernel_launch(void* const* d_in, const int* in_sizes, int n_in,
                              void* d_out, int out_size, void* d_ws, size_t ws_size,
                              hipStream_t stream) {
    const float* x   = (const float*)d_in[0];
    const int*   len = (const int*)  d_in[1];
    const float* Wf  = (const float*)d_in[3];
    const float* Uf  = (const float*)d_in[4];
    const float* bfv = (const float*)d_in[5];
    const float* Wb  = (const float*)d_in[6];
    const float* Ub  = (const float*)d_in[7];
    const float* bbv = (const float*)d_in[8];
    float* outp = (float*)d_out;

    char* w = (char*)d_ws;
    f16*      x16hp = (f16*)w;                         // 20,971,520 B
    f16*      x16lp = (f16*)(w + 20971520);            // 20,971,520 B
    f16*      wpkp  = (f16*)(w + 41943040);            //  6,144,000 B
    f16*      upkp  = (f16*)(w + 48087040);            //  5,836,800 B
    f16*      hbufp = (f16*)(w + 53923840);            //    327,680 B
    float*    xzp   = (float*)(w + 54251520);          // 50*13*64*96*4 = 15,974,400 B
    unsigned* flagp = (unsigned*)(w + 70225920);       //      4,096 B
    int*      maxtp = (int*)(w + 70230016);

    hipLaunchKernelGGL(lstm_prep, dim3(1024), dim3(256), 0, stream,
                       x, Wf, Uf, Wb, Ub, len,
                       x16hp, x16lp, wpkp, upkp, (unsigned*)hbufp, flagp, maxtp, outp);

    hipLaunchKernelGGL(lstm_main, dim3(GRID_MAIN), dim3(256), 0, stream,
                       x16hp, x16lp, wpkp, upkp, hbufp, xzp, flagp, maxtp, len, bfv, bbv, outp);
}